// Round 12
// baseline (483.717 us; speedup 1.0000x reference)
//
#include <hip/hip_runtime.h>
#include <hip/hip_bf16.h>

typedef __attribute__((ext_vector_type(8))) short short8;
typedef __attribute__((ext_vector_type(4))) short short4v;
typedef __attribute__((ext_vector_type(4))) float float4v;
typedef __attribute__((ext_vector_type(2))) unsigned uint2v;

#define NB 8
#define NH 12
#define NN 1024
#define ND 64
#define NC 768

#define RAWBAR() do { \
  asm volatile("s_waitcnt lgkmcnt(0)" ::: "memory"); \
  __builtin_amdgcn_s_barrier(); \
} while (0)

__device__ __forceinline__ short f2bf(float f) {
  __hip_bfloat16 h = __float2bfloat16(f);
  union { __hip_bfloat16 h; short s; } u; u.h = h; return u.s;
}
__device__ __forceinline__ unsigned pk2(float a, float b) {
  unsigned ua = (unsigned short)f2bf(a);
  unsigned ub = (unsigned short)f2bf(b);
  return ua | (ub << 16);
}

// ---------------- GEMM: MODE 0 = QKV (A fp32, scatter to Q/K bf16 + V^T),
// ----------------       MODE 1 = proj (A bf16, +bias, fp32 out) ----------------
template<int MODE>
__global__ __launch_bounds__(256, 2)
void gemm_kernel(const void* __restrict__ Ap, const float* __restrict__ Bw,
                 const float* __restrict__ bias,
                 __hip_bfloat16* __restrict__ Qo, __hip_bfloat16* __restrict__ Ko,
                 __hip_bfloat16* __restrict__ VTo, float* __restrict__ Out)
{
  __shared__ short As[128 * 40];
  __shared__ short Bs[128 * 40];
  const int tid = threadIdx.x;
  const int w = tid >> 6, lane = tid & 63, lr = lane & 15, lg = lane >> 4;
  const int wr = w >> 1, wc = w & 1;
  const int n0 = blockIdx.x * 128, m0 = blockIdx.y * 128;

  float4v acc[4][4];
  #pragma unroll
  for (int i = 0; i < 4; i++)
    #pragma unroll
    for (int j = 0; j < 4; j++)
      acc[i][j] = (float4v){0.f, 0.f, 0.f, 0.f};

  for (int kt = 0; kt < 768; kt += 32) {
    if (MODE == 0) {
      const float* A = (const float*)Ap;
      #pragma unroll
      for (int i2 = 0; i2 < 4; i2++) {
        int c = tid + 256 * i2;
        int row = c >> 3, c4 = c & 7;
        float4v v = *(const float4v*)(A + (size_t)(m0 + row) * 768 + kt + c4 * 4);
        short4v s = { f2bf(v[0]), f2bf(v[1]), f2bf(v[2]), f2bf(v[3]) };
        *(short4v*)(&As[row * 40 + c4 * 4]) = s;
      }
    } else {
      const __hip_bfloat16* A = (const __hip_bfloat16*)Ap;
      #pragma unroll
      for (int i2 = 0; i2 < 2; i2++) {
        int c = tid + 256 * i2;
        int row = c >> 2, c8 = c & 3;
        *(short8*)(&As[row * 40 + c8 * 8]) =
            *(const short8*)(A + (size_t)(m0 + row) * 768 + kt + c8 * 8);
      }
    }
    #pragma unroll
    for (int i2 = 0; i2 < 4; i2++) {
      int c = tid + 256 * i2;
      int row = c >> 3, c4 = c & 7;
      float4v v = *(const float4v*)(Bw + (size_t)(n0 + row) * 768 + kt + c4 * 4);
      short4v s = { f2bf(v[0]), f2bf(v[1]), f2bf(v[2]), f2bf(v[3]) };
      *(short4v*)(&Bs[row * 40 + c4 * 4]) = s;
    }
    __syncthreads();

    short8 af[4], bfr[4];
    #pragma unroll
    for (int i = 0; i < 4; i++)
      af[i] = *(const short8*)(&As[(wr * 64 + i * 16 + lr) * 40 + lg * 8]);
    #pragma unroll
    for (int j = 0; j < 4; j++)
      bfr[j] = *(const short8*)(&Bs[(wc * 64 + j * 16 + lr) * 40 + lg * 8]);
    #pragma unroll
    for (int i = 0; i < 4; i++)
      #pragma unroll
      for (int j = 0; j < 4; j++)
        acc[i][j] = __builtin_amdgcn_mfma_f32_16x16x32_bf16(af[i], bfr[j], acc[i][j], 0, 0, 0);
    __syncthreads();
  }

  #pragma unroll
  for (int i = 0; i < 4; i++) {
    #pragma unroll
    for (int j = 0; j < 4; j++) {
      #pragma unroll
      for (int r = 0; r < 4; r++) {
        float val = acc[i][j][r];
        int mg_ = m0 + wr * 64 + i * 16 + lg * 4 + r;
        int ng_ = n0 + wc * 64 + j * 16 + lr;
        if (MODE == 0) {
          int s = ng_ / 768;
          int rem = ng_ - s * 768;
          int h = rem >> 6, d = rem & 63;
          int b = mg_ >> 10, n = mg_ & 1023;
          if (s == 0)
            Qo[(((size_t)b * NH + h) * NN + n) * ND + d] = __float2bfloat16(val * 0.125f);
          else if (s == 1)
            Ko[(((size_t)b * NH + h) * NN + n) * ND + d] = __float2bfloat16(val);
          else  // V stored transposed: VT[b][h][d][m]
            VTo[(((size_t)b * NH + h) * ND + d) * NN + n] = __float2bfloat16(val);
        } else {
          Out[(size_t)mg_ * NC + ng_] = val + bias[ng_];
        }
      }
    }
  }
}

// ---------------- Pass 1: QK + conv_l + exp -> P~ (global, compact) + invL ----------------
// grid 512 x 256 (4 waves). b=blk&7, n0=(blk>>3)*16. R8 segment structure, 33 segments.
// P~ tile layout (per block, per tile t): 32 chunks x 192 shorts:
//   chunk = [pos 16][k0..7] (128 sh) then [pos 16][k8..11] (64 sh).
__global__ __launch_bounds__(256, 2)
void attn_l_kernel(const __hip_bfloat16* __restrict__ Qg, const __hip_bfloat16* __restrict__ Kg,
                   const float* __restrict__ convl,
                   short* __restrict__ Pg, float* __restrict__ Lg)
{
  __shared__ short Sb[18688];      // 2 bufs x 32 chunks x 292 shorts
  __shared__ short lwA[512];       // lw A-frag [o(16)][h(32)], zero-padded

  const int tid = threadIdx.x;
  const int w = tid >> 6, lane = tid & 63, lr = lane & 15, lg = lane >> 4;
  const int b = blockIdx.x & 7;
  const int n0 = (blockIdx.x >> 3) * 16;
  const float4v zf = (float4v){0.f, 0.f, 0.f, 0.f};

  for (int i = tid; i < 512; i += 256) {
    int r = i >> 5, k = i & 31;
    lwA[i] = (r < 12 && k < 12) ? f2bf(convl[r * 12 + k]) : (short)0;
  }
  for (int i = tid; i < 9344; i += 256) ((unsigned*)Sb)[i] = 0u;

  short8 qf[3][2];
  #pragma unroll
  for (int hh = 0; hh < 3; hh++)
    #pragma unroll
    for (int ks = 0; ks < 2; ks++)
      qf[hh][ks] = *(const short8*)(Qg +
          (((size_t)b * NH + w * 3 + hh) * NN + n0 + lr) * ND + ks * 32 + lg * 8);

  short8 kreg[3][2][2];
  auto loadK = [&](int t) {
    #pragma unroll
    for (int hh = 0; hh < 3; hh++) {
      const size_t kbase = (((size_t)b * NH + w * 3 + hh) * NN + t * 32) * ND;
      #pragma unroll
      for (int j = 0; j < 2; j++)
        #pragma unroll
        for (int ks = 0; ks < 2; ks++)
          kreg[hh][j][ks] = *(const short8*)(Kg + kbase +
              (size_t)(j * 16 + lr) * ND + ks * 32 + lg * 8);
    }
  };

  short* Pblk = Pg + (size_t)blockIdx.x * 32 * 6144;

  loadK(0);
  RAWBAR();
  const short8 lwf = *(const short8*)(&lwA[lr * 32 + lg * 8]);  // A[row=o][k=h]

  float Lacc[4][4];
  #pragma unroll
  for (int r = 0; r < 4; r++)
    #pragma unroll
    for (int nn = 0; nn < 4; nn++) Lacc[r][nn] = 0.f;

  for (int t = 0; t <= 32; t++) {
    __builtin_amdgcn_s_setprio(1);
    if (t < 32) {
      const int bufc = (t & 1) * 32;
      #pragma unroll
      for (int hh = 0; hh < 3; hh++) {
        const int h = w * 3 + hh;
        #pragma unroll
        for (int j = 0; j < 2; j++) {
          float4v a = __builtin_amdgcn_mfma_f32_16x16x32_bf16(qf[hh][0], kreg[hh][j][0], zf, 0, 0, 0);
          a = __builtin_amdgcn_mfma_f32_16x16x32_bf16(qf[hh][1], kreg[hh][j][1], a, 0, 0, 0);
          #pragma unroll
          for (int r = 0; r < 4; r++)
            Sb[(bufc + (lg * 4 + r) * 2 + j) * 292 + lr * 18 + h] = f2bf(a[r]);
        }
      }
      if (t < 31) loadK(t + 1);
    }
    __builtin_amdgcn_s_setprio(0);
    if (t >= 1) {
      const int bufc = ((t - 1) & 1) * 32;
      short* Pt = Pblk + (size_t)(t - 1) * 6144;
      #pragma unroll
      for (int cc = 0; cc < 8; cc++) {
        const int c = w * 8 + cc;
        short8 sb = *(const short8*)(&Sb[(bufc + c) * 292 + lr * 18 + lg * 8]);
        float4v d = __builtin_amdgcn_mfma_f32_16x16x32_bf16(lwf, sb, zf, 0, 0, 0);
        float e0 = __expf(d[0]), e1 = __expf(d[1]);
        float e2 = __expf(d[2]), e3 = __expf(d[3]);
        Lacc[0][cc >> 1] += e0; Lacc[1][cc >> 1] += e1;
        Lacc[2][cc >> 1] += e2; Lacc[3][cc >> 1] += e3;
        if (lg < 3) {   // store P~ rows o = lg*4..lg*4+3 (o<12)
          uint2v st = { pk2(e0, e1), pk2(e2, e3) };
          int soff = (lg < 2) ? (lr * 8 + lg * 4) : (128 + lr * 4);
          *(uint2v*)(Pt + (size_t)c * 192 + soff) = st;
        }
      }
    }
    RAWBAR();
  }

  #pragma unroll
  for (int r = 0; r < 4; r++)
    #pragma unroll
    for (int nn = 0; nn < 4; nn++) {
      float v = Lacc[r][nn];
      v += __shfl_xor(v, 1);
      v += __shfl_xor(v, 2);
      v += __shfl_xor(v, 4);
      v += __shfl_xor(v, 8);
      int o = lg * 4 + r;
      if (lr == 0 && o < 12)
        Lg[((size_t)b * NH + o) * NN + n0 + w * 4 + nn] = 1.0f / v;
    }
}

// ---------------- Pass 2: pm = (ww*invL) @ P~ ; out = VT @ pm^T ----------------
// grid 512 x 256 (4 waves). No QK/conv_l/exp. P~ A-frags reg double-buffered.
__global__ __launch_bounds__(256, 1)
void attn_pv_kernel(const __hip_bfloat16* __restrict__ VTg, const float* __restrict__ convw,
                    const float* __restrict__ Lg, const short* __restrict__ Pg,
                    __hip_bfloat16* __restrict__ AOut)
{
  __shared__ short pm[18688];      // 2 bufs x 16 o2 x 584 shorts

  const int tid = threadIdx.x;
  const int w = tid >> 6, lane = tid & 63, lr = lane & 15, lg = lane >> 4;
  const int b = blockIdx.x & 7;
  const int n0 = (blockIdx.x >> 3) * 16;
  const float4v zf = (float4v){0.f, 0.f, 0.f, 0.f};

  // wwS[nn]: B-frag [col=o2=lr][k=o=lg*8+j] = ww[o2][o] * invL[o][n0+w*4+nn], bf16
  short8 wwS[4];
  #pragma unroll
  for (int nn = 0; nn < 4; nn++) {
    const int n = n0 + w * 4 + nn;
    #pragma unroll
    for (int j = 0; j < 8; j++) {
      const int o = lg * 8 + j;
      float wv = (lr < 12 && o < 12) ? convw[lr * 12 + o] : 0.f;
      float iv = (o < 12) ? Lg[((size_t)b * NH + o) * NN + n] : 0.f;
      wwS[nn][j] = f2bf(wv * iv);
    }
  }

  const short* Pblk = Pg + (size_t)blockIdx.x * 32 * 6144;
  const __hip_bfloat16* Vw = VTg + (((size_t)b * NH + w * 3) * ND) * NN;
  const int vlane = lr * NN + lg * 8;

  short8 PA[8], PB[8];
  auto loadP = [&](int t, short8 (&PD)[8]) {
    const short* Pt = Pblk + (size_t)t * 6144;
    #pragma unroll
    for (int cc = 0; cc < 8; cc++) {
      const int c = w * 8 + cc;
      short8 v = (short8)(short)0;
      if (lg == 0) {
        v = *(const short8*)(Pt + (size_t)c * 192 + lr * 8);           // k0..7
      } else if (lg == 1) {
        short4v t4 = *(const short4v*)(Pt + (size_t)c * 192 + 128 + lr * 4);  // k8..11
        v[0] = t4[0]; v[1] = t4[1]; v[2] = t4[2]; v[3] = t4[3];
      }
      PD[cc] = v;   // lg>=2 (k>=16) and k12..15 are zero; killed by wwS zeros anyway
    }
  };

  float4v oacc[3][4];
  #pragma unroll
  for (int hh = 0; hh < 3; hh++)
    #pragma unroll
    for (int jd = 0; jd < 4; jd++) oacc[hh][jd] = zf;

  // segment T: pf(T-1) | vt(T-1) | loadP(T+1) | conv_w(T) from cur | PV(T-1) | bar
  auto seg = [&](int T, short8 (&Pcur)[8], short8 (&Pnext)[8]) {
    short8 pf[3];
    short8 vt[3][4];
    if (T >= 1) {
      const int pmb = ((T - 1) & 1) * 9344;
      #pragma unroll
      for (int hh = 0; hh < 3; hh++)
        pf[hh] = *(const short8*)(&pm[pmb + (w * 3 + hh) * 584 + lr * 36 + lg * 8]);
      const int m0v = (T - 1) * 32;
      #pragma unroll
      for (int hh = 0; hh < 3; hh++)
        #pragma unroll
        for (int jd = 0; jd < 4; jd++)
          vt[hh][jd] = *(const short8*)(Vw + hh * (ND * NN) + jd * 16 * NN + m0v + vlane);
    }
    if (T + 1 < 32) loadP(T + 1, Pnext);
    if (T < 32) {
      const int pmb = (T & 1) * 9344;
      __builtin_amdgcn_s_setprio(1);
      #pragma unroll
      for (int cc = 0; cc < 8; cc++) {
        const int c = w * 8 + cc;
        float4v d = __builtin_amdgcn_mfma_f32_16x16x32_bf16(Pcur[cc], wwS[cc >> 1], zf, 0, 0, 0);
        unsigned* dst = (unsigned*)(&pm[pmb + lr * 584 + (c >> 1) * 36 + (c & 1) * 16 + lg * 4]);
        dst[0] = pk2(d[0], d[1]);
        dst[1] = pk2(d[2], d[3]);
      }
      __builtin_amdgcn_s_setprio(0);
    }
    if (T >= 1) {
      __builtin_amdgcn_s_setprio(1);
      #pragma unroll
      for (int hh = 0; hh < 3; hh++)
        #pragma unroll
        for (int jd = 0; jd < 4; jd++)
          oacc[hh][jd] = __builtin_amdgcn_mfma_f32_16x16x32_bf16(vt[hh][jd], pf[hh], oacc[hh][jd], 0, 0, 0);
      __builtin_amdgcn_s_setprio(0);
    }
    RAWBAR();
  };

  loadP(0, PA);
  for (int tp = 0; tp <= 32; tp += 2) {
    seg(tp, PA, PB);
    if (tp + 1 <= 32) seg(tp + 1, PB, PA);
  }

  // epilogue: lane holds (o2, d = jd*16+lg*4.., n = n0+lr)
  #pragma unroll
  for (int hh = 0; hh < 3; hh++) {
    const int o2 = w * 3 + hh;
    #pragma unroll
    for (int jd = 0; jd < 4; jd++) {
      size_t base = ((size_t)b * NN + n0 + lr) * NC + o2 * 64 + jd * 16 + lg * 4;
      unsigned* dst = (unsigned*)(&AOut[base]);
      dst[0] = pk2(oacc[hh][jd][0], oacc[hh][jd][1]);
      dst[1] = pk2(oacc[hh][jd][2], oacc[hh][jd][3]);
    }
  }
}

extern "C" void kernel_launch(void* const* d_in, const int* in_sizes, int n_in,
                              void* d_out, int out_size, void* d_ws, size_t ws_size,
                              hipStream_t stream) {
  const float* x      = (const float*)d_in[0];
  const float* w_qkv  = (const float*)d_in[1];
  const float* w_proj = (const float*)d_in[2];
  const float* b_proj = (const float*)d_in[3];
  const float* conv_l = (const float*)d_in[4];
  const float* conv_w = (const float*)d_in[5];
  float* out = (float*)d_out;

  const size_t NE = (size_t)NB * NH * NN * ND;
  __hip_bfloat16* Qb = (__hip_bfloat16*)d_ws;
  __hip_bfloat16* Kb = Qb + NE;
  __hip_bfloat16* VT = Kb + NE;
  __hip_bfloat16* AO = VT + NE;                   // [B*N][C] bf16
  float* Lg = (float*)(AO + NE);                  // 8*12*1024 floats (invL)
  short* Pg = (short*)(Lg + (size_t)NB * NH * NN);  // 512*32*6144 shorts = 201.3 MB

  gemm_kernel<0><<<dim3(18, 64), 256, 0, stream>>>(x, w_qkv, nullptr, Qb, Kb, VT, nullptr);
  attn_l_kernel<<<dim3(512), 256, 0, stream>>>(Qb, Kb, conv_l, Pg, Lg);
  attn_pv_kernel<<<dim3(512), 256, 0, stream>>>(VT, conv_w, Lg, Pg, AO);
  gemm_kernel<1><<<dim3(6, 64), 256, 0, stream>>>(AO, w_proj, b_proj, nullptr, nullptr, nullptr, out);
}

// Round 13
// 391.058 us; speedup vs baseline: 1.2369x; 1.2369x over previous
//
#include <hip/hip_runtime.h>
#include <hip/hip_bf16.h>

typedef __attribute__((ext_vector_type(8))) short short8;
typedef __attribute__((ext_vector_type(4))) short short4v;
typedef __attribute__((ext_vector_type(4))) float float4v;
typedef __attribute__((ext_vector_type(2))) unsigned uint2v;

#define NB 8
#define NH 12
#define NN 1024
#define ND 64
#define NC 768

#define RAWBAR() do { \
  asm volatile("s_waitcnt lgkmcnt(0)" ::: "memory"); \
  __builtin_amdgcn_s_barrier(); \
} while (0)

__device__ __forceinline__ short f2bf(float f) {
  __hip_bfloat16 h = __float2bfloat16(f);
  union { __hip_bfloat16 h; short s; } u; u.h = h; return u.s;
}
__device__ __forceinline__ unsigned pk2(float a, float b) {
  unsigned ua = (unsigned short)f2bf(a);
  unsigned ub = (unsigned short)f2bf(b);
  return ua | (ub << 16);
}

// ---------------- GEMM: MODE 0 = QKV (A fp32 -> Q bf16 + fragment-layout Kf/Vf),
// ----------------       MODE 1 = proj (A bf16, +bias, fp32 out) ----------------
// Kf: block (b,h,t,j,ks) of 1KB; lane' = ((d>>3)&3)*16 + (n&15); short (d&7).
//     -> QK B-frag load = base + lane*16B, contiguous 1KB.
// Vf: block (b,h,t,jd) of 1KB; lane' = ((n>>3)&3)*16 + (d&15); short (n&7).
//     -> PV A-frag load = base + lane*16B, contiguous 1KB.
template<int MODE>
__global__ __launch_bounds__(256, 2)
void gemm_kernel(const void* __restrict__ Ap, const float* __restrict__ Bw,
                 const float* __restrict__ bias,
                 __hip_bfloat16* __restrict__ Qo, __hip_bfloat16* __restrict__ Kf,
                 __hip_bfloat16* __restrict__ Vf, float* __restrict__ Out)
{
  __shared__ short As[128 * 40];
  __shared__ short Bs[128 * 40];
  const int tid = threadIdx.x;
  const int w = tid >> 6, lane = tid & 63, lr = lane & 15, lg = lane >> 4;
  const int wr = w >> 1, wc = w & 1;
  const int n0 = blockIdx.x * 128, m0 = blockIdx.y * 128;

  float4v acc[4][4];
  #pragma unroll
  for (int i = 0; i < 4; i++)
    #pragma unroll
    for (int j = 0; j < 4; j++)
      acc[i][j] = (float4v){0.f, 0.f, 0.f, 0.f};

  for (int kt = 0; kt < 768; kt += 32) {
    if (MODE == 0) {
      const float* A = (const float*)Ap;
      #pragma unroll
      for (int i2 = 0; i2 < 4; i2++) {
        int c = tid + 256 * i2;
        int row = c >> 3, c4 = c & 7;
        float4v v = *(const float4v*)(A + (size_t)(m0 + row) * 768 + kt + c4 * 4);
        short4v s = { f2bf(v[0]), f2bf(v[1]), f2bf(v[2]), f2bf(v[3]) };
        *(short4v*)(&As[row * 40 + c4 * 4]) = s;
      }
    } else {
      const __hip_bfloat16* A = (const __hip_bfloat16*)Ap;
      #pragma unroll
      for (int i2 = 0; i2 < 2; i2++) {
        int c = tid + 256 * i2;
        int row = c >> 2, c8 = c & 3;
        *(short8*)(&As[row * 40 + c8 * 8]) =
            *(const short8*)(A + (size_t)(m0 + row) * 768 + kt + c8 * 8);
      }
    }
    #pragma unroll
    for (int i2 = 0; i2 < 4; i2++) {
      int c = tid + 256 * i2;
      int row = c >> 3, c4 = c & 7;
      float4v v = *(const float4v*)(Bw + (size_t)(n0 + row) * 768 + kt + c4 * 4);
      short4v s = { f2bf(v[0]), f2bf(v[1]), f2bf(v[2]), f2bf(v[3]) };
      *(short4v*)(&Bs[row * 40 + c4 * 4]) = s;
    }
    __syncthreads();

    short8 af[4], bfr[4];
    #pragma unroll
    for (int i = 0; i < 4; i++)
      af[i] = *(const short8*)(&As[(wr * 64 + i * 16 + lr) * 40 + lg * 8]);
    #pragma unroll
    for (int j = 0; j < 4; j++)
      bfr[j] = *(const short8*)(&Bs[(wc * 64 + j * 16 + lr) * 40 + lg * 8]);
    #pragma unroll
    for (int i = 0; i < 4; i++)
      #pragma unroll
      for (int j = 0; j < 4; j++)
        acc[i][j] = __builtin_amdgcn_mfma_f32_16x16x32_bf16(af[i], bfr[j], acc[i][j], 0, 0, 0);
    __syncthreads();
  }

  #pragma unroll
  for (int i = 0; i < 4; i++) {
    #pragma unroll
    for (int j = 0; j < 4; j++) {
      #pragma unroll
      for (int r = 0; r < 4; r++) {
        float val = acc[i][j][r];
        int mg_ = m0 + wr * 64 + i * 16 + lg * 4 + r;
        int ng_ = n0 + wc * 64 + j * 16 + lr;
        if (MODE == 0) {
          int s = ng_ / 768;
          int rem = ng_ - s * 768;
          int h = rem >> 6, d = rem & 63;
          int b = mg_ >> 10, n = mg_ & 1023;
          if (s == 0) {
            Qo[(((size_t)b * NH + h) * NN + n) * ND + d] = __float2bfloat16(val * 0.125f);
          } else if (s == 1) {
            int t = n >> 5, jj = (n >> 4) & 1, ks2 = d >> 5;
            int lanep = ((d >> 3) & 3) * 16 + (n & 15);
            size_t off = (((((size_t)b * NH + h) * 32 + t) * 2 + jj) * 2 + ks2) * 512
                         + lanep * 8 + (d & 7);
            Kf[off] = __float2bfloat16(val);
          } else {
            int t = n >> 5, jd = d >> 4;
            int lanep = ((n >> 3) & 3) * 16 + (d & 15);
            size_t off = ((((size_t)b * NH + h) * 32 + t) * 4 + jd) * 512
                         + lanep * 8 + (n & 7);
            Vf[off] = __float2bfloat16(val);
          }
        } else {
          Out[(size_t)mg_ * NC + ng_] = val + bias[ng_];
        }
      }
    }
  }
}

// ---------------- Pass 1: QK + conv_l + exp -> P~ (global, compact) + invL ----------------
// grid 512 x 256 (4 waves). b=blk&7, n0=(blk>>3)*16. 33 one-barrier segments.
// P~ tile: 32 chunks x 192 shorts: chunk = [pos 16][k0..7](128sh) + [pos 16][k8..11](64sh).
__global__ __launch_bounds__(256, 2)
void attn_l_kernel(const __hip_bfloat16* __restrict__ Qg, const __hip_bfloat16* __restrict__ Kf,
                   const float* __restrict__ convl,
                   short* __restrict__ Pg, float* __restrict__ Lg)
{
  __shared__ short Sb[18688];      // 2 bufs x 32 chunks x 292 shorts
  __shared__ short lwA[512];       // lw A-frag [o(16)][h(32)], zero-padded

  const int tid = threadIdx.x;
  const int w = tid >> 6, lane = tid & 63, lr = lane & 15, lg = lane >> 4;
  const int b = blockIdx.x & 7;
  const int n0 = (blockIdx.x >> 3) * 16;
  const float4v zf = (float4v){0.f, 0.f, 0.f, 0.f};

  for (int i = tid; i < 512; i += 256) {
    int r = i >> 5, k = i & 31;
    lwA[i] = (r < 12 && k < 12) ? f2bf(convl[r * 12 + k]) : (short)0;
  }
  for (int i = tid; i < 9344; i += 256) ((unsigned*)Sb)[i] = 0u;

  short8 qf[3][2];
  #pragma unroll
  for (int hh = 0; hh < 3; hh++)
    #pragma unroll
    for (int ks = 0; ks < 2; ks++)
      qf[hh][ks] = *(const short8*)(Qg +
          (((size_t)b * NH + w * 3 + hh) * NN + n0 + lr) * ND + ks * 32 + lg * 8);

  // fragment-contiguous K loads: one 16B load per frag at base + lane*16B
  const short* Kw = (const short*)Kf + ((size_t)(b * NH + w * 3) * 32) * 2048 + lane * 8;
  short8 kreg[3][2][2];
  auto loadK = [&](int t) {
    #pragma unroll
    for (int hh = 0; hh < 3; hh++)
      #pragma unroll
      for (int j = 0; j < 2; j++)
        #pragma unroll
        for (int ks = 0; ks < 2; ks++)
          kreg[hh][j][ks] = *(const short8*)(Kw + hh * 65536 + t * 2048 + (j * 2 + ks) * 512);
  };

  short* Pblk = Pg + (size_t)blockIdx.x * 32 * 6144;

  loadK(0);
  RAWBAR();
  const short8 lwf = *(const short8*)(&lwA[lr * 32 + lg * 8]);  // A[row=o][k=h]

  float Lacc[4][4];
  #pragma unroll
  for (int r = 0; r < 4; r++)
    #pragma unroll
    for (int nn = 0; nn < 4; nn++) Lacc[r][nn] = 0.f;

  for (int t = 0; t <= 32; t++) {
    __builtin_amdgcn_s_setprio(1);
    if (t < 32) {
      const int bufc = (t & 1) * 32;
      #pragma unroll
      for (int hh = 0; hh < 3; hh++) {
        const int h = w * 3 + hh;
        #pragma unroll
        for (int j = 0; j < 2; j++) {
          float4v a = __builtin_amdgcn_mfma_f32_16x16x32_bf16(qf[hh][0], kreg[hh][j][0], zf, 0, 0, 0);
          a = __builtin_amdgcn_mfma_f32_16x16x32_bf16(qf[hh][1], kreg[hh][j][1], a, 0, 0, 0);
          #pragma unroll
          for (int r = 0; r < 4; r++)
            Sb[(bufc + (lg * 4 + r) * 2 + j) * 292 + lr * 18 + h] = f2bf(a[r]);
        }
      }
      if (t < 31) loadK(t + 1);
    }
    __builtin_amdgcn_s_setprio(0);
    if (t >= 1) {
      const int bufc = ((t - 1) & 1) * 32;
      short* Pt = Pblk + (size_t)(t - 1) * 6144;
      #pragma unroll
      for (int cc = 0; cc < 8; cc++) {
        const int c = w * 8 + cc;
        short8 sb = *(const short8*)(&Sb[(bufc + c) * 292 + lr * 18 + lg * 8]);
        float4v d = __builtin_amdgcn_mfma_f32_16x16x32_bf16(lwf, sb, zf, 0, 0, 0);
        float e0 = __expf(d[0]), e1 = __expf(d[1]);
        float e2 = __expf(d[2]), e3 = __expf(d[3]);
        Lacc[0][cc >> 1] += e0; Lacc[1][cc >> 1] += e1;
        Lacc[2][cc >> 1] += e2; Lacc[3][cc >> 1] += e3;
        if (lg < 3) {   // store P~ rows o = lg*4..lg*4+3 (o<12)
          uint2v st = { pk2(e0, e1), pk2(e2, e3) };
          int soff = (lg < 2) ? (lr * 8 + lg * 4) : (128 + lr * 4);
          *(uint2v*)(Pt + (size_t)c * 192 + soff) = st;
        }
      }
    }
    RAWBAR();
  }

  #pragma unroll
  for (int r = 0; r < 4; r++)
    #pragma unroll
    for (int nn = 0; nn < 4; nn++) {
      float v = Lacc[r][nn];
      v += __shfl_xor(v, 1);
      v += __shfl_xor(v, 2);
      v += __shfl_xor(v, 4);
      v += __shfl_xor(v, 8);
      int o = lg * 4 + r;
      if (lr == 0 && o < 12)
        Lg[((size_t)b * NH + o) * NN + n0 + w * 4 + nn] = 1.0f / v;
    }
}

// ---------------- Pass 2: pm = (ww*invL) @ P~ ; out = VT @ pm^T ----------------
// grid 512 x 256 (4 waves). V loads fragment-contiguous; P~ reg double-buffered.
__global__ __launch_bounds__(256, 1)
void attn_pv_kernel(const __hip_bfloat16* __restrict__ Vf, const float* __restrict__ convw,
                    const float* __restrict__ Lg, const short* __restrict__ Pg,
                    __hip_bfloat16* __restrict__ AOut)
{
  __shared__ short pm[18688];      // 2 bufs x 16 o2 x 584 shorts

  const int tid = threadIdx.x;
  const int w = tid >> 6, lane = tid & 63, lr = lane & 15, lg = lane >> 4;
  const int b = blockIdx.x & 7;
  const int n0 = (blockIdx.x >> 3) * 16;
  const float4v zf = (float4v){0.f, 0.f, 0.f, 0.f};

  // wwS[nn]: B-frag [col=o2=lr][k=o=lg*8+j] = ww[o2][o] * invL[o][n0+w*4+nn], bf16
  short8 wwS[4];
  #pragma unroll
  for (int nn = 0; nn < 4; nn++) {
    const int n = n0 + w * 4 + nn;
    #pragma unroll
    for (int j = 0; j < 8; j++) {
      const int o = lg * 8 + j;
      float wv = (lr < 12 && o < 12) ? convw[lr * 12 + o] : 0.f;
      float iv = (o < 12) ? Lg[((size_t)b * NH + o) * NN + n] : 0.f;
      wwS[nn][j] = f2bf(wv * iv);
    }
  }

  const short* Pblk = Pg + (size_t)blockIdx.x * 32 * 6144;
  const short* Vw = (const short*)Vf + ((size_t)(b * NH + w * 3) * 32) * 2048 + lane * 8;

  short8 PA[8], PB[8];
  auto loadP = [&](int t, short8 (&PD)[8]) {
    const short* Pt = Pblk + (size_t)t * 6144;
    #pragma unroll
    for (int cc = 0; cc < 8; cc++) {
      const int c = w * 8 + cc;
      short8 v = (short8)(short)0;
      if (lg == 0) {
        v = *(const short8*)(Pt + (size_t)c * 192 + lr * 8);           // k0..7
      } else if (lg == 1) {
        short4v t4 = *(const short4v*)(Pt + (size_t)c * 192 + 128 + lr * 4);  // k8..11
        v[0] = t4[0]; v[1] = t4[1]; v[2] = t4[2]; v[3] = t4[3];
      }
      PD[cc] = v;   // k>=12 zero; killed by wwS zeros anyway
    }
  };

  float4v oacc[3][4];
  #pragma unroll
  for (int hh = 0; hh < 3; hh++)
    #pragma unroll
    for (int jd = 0; jd < 4; jd++) oacc[hh][jd] = zf;

  // segment T: pf(T-1) | vt(T-1) (contiguous) | loadP(T+1) | conv_w(T) | PV(T-1) | bar
  auto seg = [&](int T, short8 (&Pcur)[8], short8 (&Pnext)[8]) {
    short8 pf[3];
    short8 vt[3][4];
    if (T >= 1) {
      const int pmb = ((T - 1) & 1) * 9344;
      #pragma unroll
      for (int hh = 0; hh < 3; hh++)
        pf[hh] = *(const short8*)(&pm[pmb + (w * 3 + hh) * 584 + lr * 36 + lg * 8]);
      #pragma unroll
      for (int hh = 0; hh < 3; hh++)
        #pragma unroll
        for (int jd = 0; jd < 4; jd++)
          vt[hh][jd] = *(const short8*)(Vw + hh * 65536 + (T - 1) * 2048 + jd * 512);
    }
    if (T + 1 < 32) loadP(T + 1, Pnext);
    if (T < 32) {
      const int pmb = (T & 1) * 9344;
      __builtin_amdgcn_s_setprio(1);
      #pragma unroll
      for (int cc = 0; cc < 8; cc++) {
        const int c = w * 8 + cc;
        float4v d = __builtin_amdgcn_mfma_f32_16x16x32_bf16(Pcur[cc], wwS[cc >> 1], zf, 0, 0, 0);
        unsigned* dst = (unsigned*)(&pm[pmb + lr * 584 + (c >> 1) * 36 + (c & 1) * 16 + lg * 4]);
        dst[0] = pk2(d[0], d[1]);
        dst[1] = pk2(d[2], d[3]);
      }
      __builtin_amdgcn_s_setprio(0);
    }
    if (T >= 1) {
      __builtin_amdgcn_s_setprio(1);
      #pragma unroll
      for (int hh = 0; hh < 3; hh++)
        #pragma unroll
        for (int jd = 0; jd < 4; jd++)
          oacc[hh][jd] = __builtin_amdgcn_mfma_f32_16x16x32_bf16(vt[hh][jd], pf[hh], oacc[hh][jd], 0, 0, 0);
      __builtin_amdgcn_s_setprio(0);
    }
    RAWBAR();
  };

  loadP(0, PA);
  for (int tp = 0; tp <= 32; tp += 2) {
    seg(tp, PA, PB);
    if (tp + 1 <= 32) seg(tp + 1, PB, PA);
  }

  // epilogue: lane holds (o2, d = jd*16+lg*4.., n = n0+lr)
  #pragma unroll
  for (int hh = 0; hh < 3; hh++) {
    const int o2 = w * 3 + hh;
    #pragma unroll
    for (int jd = 0; jd < 4; jd++) {
      size_t base = ((size_t)b * NN + n0 + lr) * NC + o2 * 64 + jd * 16 + lg * 4;
      unsigned* dst = (unsigned*)(&AOut[base]);
      dst[0] = pk2(oacc[hh][jd][0], oacc[hh][jd][1]);
      dst[1] = pk2(oacc[hh][jd][2], oacc[hh][jd][3]);
    }
  }
}

extern "C" void kernel_launch(void* const* d_in, const int* in_sizes, int n_in,
                              void* d_out, int out_size, void* d_ws, size_t ws_size,
                              hipStream_t stream) {
  const float* x      = (const float*)d_in[0];
  const float* w_qkv  = (const float*)d_in[1];
  const float* w_proj = (const float*)d_in[2];
  const float* b_proj = (const float*)d_in[3];
  const float* conv_l = (const float*)d_in[4];
  const float* conv_w = (const float*)d_in[5];
  float* out = (float*)d_out;

  const size_t NE = (size_t)NB * NH * NN * ND;
  __hip_bfloat16* Qb = (__hip_bfloat16*)d_ws;
  __hip_bfloat16* Kf = Qb + NE;
  __hip_bfloat16* Vf = Kf + NE;
  __hip_bfloat16* AO = Vf + NE;                   // [B*N][C] bf16
  float* Lg = (float*)(AO + NE);                  // 8*12*1024 floats (invL)
  short* Pg = (short*)(Lg + (size_t)NB * NH * NN);  // 512*32*6144 shorts = 201.3 MB

  gemm_kernel<0><<<dim3(18, 64), 256, 0, stream>>>(x, w_qkv, nullptr, Qb, Kf, Vf, nullptr);
  attn_l_kernel<<<dim3(512), 256, 0, stream>>>(Qb, Kf, conv_l, Pg, Lg);
  attn_pv_kernel<<<dim3(512), 256, 0, stream>>>(Vf, conv_w, Lg, Pg, AO);
  gemm_kernel<1><<<dim3(6, 64), 256, 0, stream>>>(AO, w_proj, b_proj, nullptr, nullptr, nullptr, out);
}